// Round 14
// baseline (188.037 us; speedup 1.0000x reference)
//
#include <hip/hip_runtime.h>
#include <math.h>

// Problem constants (fixed by setup_inputs)
constexpr int Bc = 256, Sc = 1024, Dc = 32, Kc = 512;
constexpr int ST = 128;                      // s-rows per main block
constexpr float LOG2E    = 1.4426950408889634f;
constexpr float LN2      = 0.6931471805599453f;
constexpr float LOG_NORM = 29.40603306051f;  // D * 0.5 * log(2*pi)

// ROUND-14: B-fragments move LDS -> REGISTERS (64 VGPR/thread, preloaded
// from a kt-major global image at kernel top; L2-resident 16 KB).
// R13's lesson: global reads are free only if latency lands under other
// work — here the 16 dwordx4 are issued ~a full prologue before first use.
// Hot-loop LDS: 24 -> 8 instrs/thread (wT only); B bank-conflicts gone;
// staging + barrier-feeding LDS writes gone. VALU/MFMA/numerics identical
// to the R9 champion (89.6us). kt-loop FULLY unrolled so breg[] is
// constant-indexed (reg-file, not scratch).
constexpr float FE_SCALE = 8388608.0f;           // 2^23
constexpr float FE_BIAS  = 1064992048.0f;        // 127*2^23 - 361168

typedef __attribute__((ext_vector_type(4))) float f32x4;
typedef __attribute__((ext_vector_type(2))) long longx2;

#if __has_builtin(__builtin_amdgcn_exp2f)
#define EXP2F(v) __builtin_amdgcn_exp2f(v)
#else
#define EXP2F(v) exp2f(v)
#endif
#if __has_builtin(__builtin_amdgcn_logf)
#define LOG2F(v) __builtin_amdgcn_logf(v)
#else
#define LOG2F(v) log2f(v)
#endif

// pack 2 f32 -> 2 e4m3 bytes; word_sel is a template constant.
template <bool HI>
__device__ __forceinline__ int pkfp8(float a, float b, int old) {
    return __builtin_amdgcn_cvt_pk_fp8_f32(a, b, old, HI);
}

// ---------------- prep: means -> kt-major e4m3 image + m2buf[512] ----------
// Thread t owns floats {2t, 2t+1} of component k=t>>4 (i = (t&15)*2).
// kt-major image: octet stream ch = (k&15)*4 + (i>>3) at ch*256 + (k>>4)*8.
// Workspace poison-fill is UNCONDITIONAL (round-2 evidence) -> d_ws is free.
__global__ __launch_bounds__(256)
void gm_m2f8(const float* __restrict__ means,
             unsigned short* __restrict__ mt8, float* __restrict__ m2buf)
{
    const int t  = blockIdx.x * 256 + threadIdx.x;   // 0..8191 (pairs)
    const float v0 = means[2 * t];
    const float v1 = means[2 * t + 1];
    const int k  = t >> 4;
    const int i  = (t & 15) * 2;
    const int ch = (k & 15) * 4 + (i >> 3);
    mt8[ch * 128 + (k >> 4) * 4 + ((i & 7) >> 1)] =
        (unsigned short)(pkfp8<false>(v0, v1, 0) & 0xffff);
    float sq = v0 * v0 + v1 * v1;
    #pragma unroll
    for (int off = 1; off <= 8; off <<= 1) sq += __shfl_xor(sq, off);
    if ((threadIdx.x & 15) == 0) m2buf[t >> 4] = sq;   // 16 pair-threads per row
}

// ---------------- main kernel ----------------
// grid(2048), 512 threads = 8 waves; wave owns ONE 16-row subtile.
//   acc = sum_k w_k * 2^(x.mu_k*log2e)  via Schraudolph fast-exp2 (R8)
//   nll = 0.5*x^2 + LOG_NORM + lse - ln2*log2(acc)
__global__ __launch_bounds__(512, 4)
void gm_main(const float* __restrict__ x, const float* __restrict__ logits,
             const float* __restrict__ m2buf, const unsigned short* __restrict__ mt8,
             float* __restrict__ out)
{
    __shared__ float wT[16 * 44];             // 2.75 KB fast-exp biases, kt-major
    __shared__ float x2p[ST];                 // 0.5 KB per-row sum(x^2)
    __shared__ float red[16];                 // [0..7] max, [8..15] expsum

    const int tid  = threadIdx.x;             // 0..511
    const int lane = tid & 63;
    const int wid  = tid >> 6;                // 0..7
    const int b    = blockIdx.x >> 3;
    const int s0   = (blockIdx.x & 7) * ST;
    const int q    = lane >> 4;               // k-octet of contraction dim
    const int ln   = lane & 15;
    const int rw   = wid * 16;                // this wave's 16-row subtile

    // B-PRELOAD: this thread's full component stream (32 kt x 8 B = 256 B)
    // into 64 VGPRs. Issued FIRST; first use is after the whole prologue,
    // so L2 (or first-touch HBM) latency is fully hidden.
    const int ch = ln * 4 + q;
    longx2 breg[16];
    {
        const longx2* bp = (const longx2*)((const char*)mt8 + ch * 256);
        #pragma unroll
        for (int j = 0; j < 16; ++j) breg[j] = bp[j];
    }

    // fast-exp weight bias Wk = (log2(w_k) + 127)*2^23 - c  (kt-major store)
    const float l = logits[b * Kc + tid];
    wT[(tid & 15) * 44 + (tid >> 4)] =
        fmaf((l - 0.5f * m2buf[tid]) * LOG2E, FE_SCALE, FE_BIAS);

    float mx = l;
    #pragma unroll
    for (int off = 32; off >= 1; off >>= 1) mx = fmaxf(mx, __shfl_xor(mx, off));
    if (lane == 0) red[wid] = mx;

    // x A-fragment direct from global (thread owns 8 of its row's 32 floats)
    const int row = rw + ln;
    long a;
    {
        const float4* xp = (const float4*)(x + ((size_t)b * Sc + s0 + row) * Dc) + q * 2;
        float4 v0 = xp[0], v1 = xp[1];
        int2 A;
        A.x = pkfp8<false>(v0.x * LOG2E, v0.y * LOG2E, 0);
        A.x = pkfp8<true >(v0.z * LOG2E, v0.w * LOG2E, A.x);
        A.y = pkfp8<false>(v1.x * LOG2E, v1.y * LOG2E, 0);
        A.y = pkfp8<true >(v1.z * LOG2E, v1.w * LOG2E, A.y);
        a = *(const long*)&A;
        float p = v0.x*v0.x + v0.y*v0.y + v0.z*v0.z + v0.w*v0.w
                + v1.x*v1.x + v1.y*v1.y + v1.z*v1.z + v1.w*v1.w;
        p += __shfl_xor(p, 16); p += __shfl_xor(p, 32);
        if (q == 0) x2p[row] = p;
    }
    __syncthreads();

    // finish lse start (max across the 8 waves parked in red[0..7])
    const float mxb = fmaxf(fmaxf(fmaxf(red[0], red[1]), fmaxf(red[2], red[3])),
                            fmaxf(fmaxf(red[4], red[5]), fmaxf(red[6], red[7])));
    float sm = EXP2F((l - mxb) * LOG2E);
    #pragma unroll
    for (int off = 32; off >= 1; off >>= 1) sm += __shfl_xor(sm, off);
    if (lane == 0) red[8 + wid] = sm;

    // hot loop: per 4-kt body = 2 REGISTER B-pairs + 1 LDS float4 (Wk, <=2-way
    // alias) + 4 MFMA + 16 fast-exp accums. LDS instrs/thread: 8 (was 24).
    const int ln44 = ln * 44;
    const f32x4 zero = {0.f, 0.f, 0.f, 0.f};
    float acc[4] = {0.f, 0.f, 0.f, 0.f};

    #pragma unroll
    for (int kt = 0; kt < 32; kt += 4) {
        const longx2 p01 = breg[(kt >> 1)];
        const longx2 p23 = breg[(kt >> 1) + 1];
        const float4 wv4 = *(const float4*)&wT[ln44 + kt];
        f32x4 d;
        d = __builtin_amdgcn_mfma_f32_16x16x32_fp8_fp8(a, p01.x, zero, 0, 0, 0);
        #pragma unroll
        for (int r = 0; r < 4; ++r)
            acc[r] += __int_as_float((int)fmaf(d[r], FE_SCALE, wv4.x));
        d = __builtin_amdgcn_mfma_f32_16x16x32_fp8_fp8(a, p01.y, zero, 0, 0, 0);
        #pragma unroll
        for (int r = 0; r < 4; ++r)
            acc[r] += __int_as_float((int)fmaf(d[r], FE_SCALE, wv4.y));
        d = __builtin_amdgcn_mfma_f32_16x16x32_fp8_fp8(a, p23.x, zero, 0, 0, 0);
        #pragma unroll
        for (int r = 0; r < 4; ++r)
            acc[r] += __int_as_float((int)fmaf(d[r], FE_SCALE, wv4.z));
        d = __builtin_amdgcn_mfma_f32_16x16x32_fp8_fp8(a, p23.y, zero, 0, 0, 0);
        #pragma unroll
        for (int r = 0; r < 4; ++r)
            acc[r] += __int_as_float((int)fmaf(d[r], FE_SCALE, wv4.w));
    }
    __syncthreads();                          // red[8..15] ready
    const float lse  = mxb + LN2 * LOG2F(((red[8]  + red[9])  + (red[10] + red[11]))
                                       + ((red[12] + red[13]) + (red[14] + red[15])));
    const float base = LOG_NORM + lse;

    // reduce over the 16 k-columns (low-4 lane bits), then write
    #pragma unroll
    for (int r = 0; r < 4; ++r) {
        float s = acc[r];
        s += __shfl_xor(s, 1); s += __shfl_xor(s, 2);
        s += __shfl_xor(s, 4); s += __shfl_xor(s, 8);
        if (ln == 0) {
            const int r0 = rw + q * 4 + r;       // C/D row = quad*4 + reg
            out[(size_t)b * Sc + s0 + r0] = 0.5f * x2p[r0] + base - LN2 * LOG2F(s);
        }
    }
}

extern "C" void kernel_launch(void* const* d_in, const int* in_sizes, int n_in,
                              void* d_out, int out_size, void* d_ws, size_t ws_size,
                              hipStream_t stream) {
    const float* x      = (const float*)d_in[0];
    const float* logits = (const float*)d_in[1];
    const float* means  = (const float*)d_in[2];
    float* out = (float*)d_out;
    (void)in_sizes; (void)n_in; (void)out_size; (void)ws_size;

    unsigned short* mt8   = (unsigned short*)d_ws;             // 16 KB kt-major fp8
    float*          m2buf = (float*)((char*)d_ws + 16384);     //  2 KB

    hipLaunchKernelGGL(gm_m2f8, dim3(32), dim3(256), 0, stream, means, mt8, m2buf);
    hipLaunchKernelGGL(gm_main, dim3(Bc * (Sc / ST)), dim3(512), 0, stream,
                       x, logits, m2buf, mt8, out);
}

// Round 15
// 89.428 us; speedup vs baseline: 2.1027x; 2.1027x over previous
//
#include <hip/hip_runtime.h>
#include <math.h>

// Problem constants (fixed by setup_inputs)
constexpr int Bc = 256, Sc = 1024, Dc = 32, Kc = 512;
constexpr int ST = 128;                      // s-rows per main block
constexpr float LOG2E    = 1.4426950408889634f;
constexpr float LN2      = 0.6931471805599453f;
constexpr float LOG_NORM = 29.40603306051f;  // D * 0.5 * log(2*pi)

// ROUND-15: RESTORE the R9 champion (89.60 us) byte-for-byte.
// R11 (32x32 MFMA), R12 (dual-subtile), R13 (wT->global), R14 (B->VGPR)
// all regressed: every LDS-offload pays in another pipe (epilogue shfl =
// LDS; MFMA serialization; exposed vmem latency; allocator-forced scratch
// spill at 64-VGPR occupancy preference). R10's amplified counters stand:
// the loop is co-saturated (LDS ~87%, VALU ~71%) — a balanced local
// optimum. Harness fixed tax ~70us dominates dur_us regardless.
constexpr float FE_SCALE = 8388608.0f;           // 2^23
constexpr float FE_BIAS  = 1064992048.0f;        // 127*2^23 - 361168

typedef __attribute__((ext_vector_type(4))) float f32x4;
typedef __attribute__((ext_vector_type(2))) long longx2;

#if __has_builtin(__builtin_amdgcn_exp2f)
#define EXP2F(v) __builtin_amdgcn_exp2f(v)
#else
#define EXP2F(v) exp2f(v)
#endif
#if __has_builtin(__builtin_amdgcn_logf)
#define LOG2F(v) __builtin_amdgcn_logf(v)
#else
#define LOG2F(v) log2f(v)
#endif

// pack 2 f32 -> 2 e4m3 bytes; word_sel is a template constant.
template <bool HI>
__device__ __forceinline__ int pkfp8(float a, float b, int old) {
    return __builtin_amdgcn_cvt_pk_fp8_f32(a, b, old, HI);
}

// ---------------- tiny prep: means -> e4m3 + m2buf[512] ----------------
// grid(32) x 256; thread owns 2 consecutive floats (coalesced 8B reads).
// Workspace poison-fill is UNCONDITIONAL (round-2 evidence) -> d_ws is free.
__global__ __launch_bounds__(256)
void gm_m2f8(const float* __restrict__ means,
             unsigned short* __restrict__ mf8, float* __restrict__ m2buf)
{
    const int t  = blockIdx.x * 256 + threadIdx.x;   // 0..8191 (pairs)
    const float v0 = means[2 * t];
    const float v1 = means[2 * t + 1];
    mf8[t] = (unsigned short)(pkfp8<false>(v0, v1, 0) & 0xffff);
    float sq = v0 * v0 + v1 * v1;
    #pragma unroll
    for (int off = 1; off <= 8; off <<= 1) sq += __shfl_xor(sq, off);
    if ((threadIdx.x & 15) == 0) m2buf[t >> 4] = sq;   // 16 pair-threads per row
}

// ---------------- main kernel ----------------
// grid(2048), 512 threads = 8 waves; wave owns ONE 16-row subtile.
//   acc = sum_k w_k * 2^(x.mu_k*log2e)  via Schraudolph fast-exp2 (R8-verified)
//   nll = 0.5*x^2 + LOG_NORM + lse - ln2*log2(acc)
__global__ __launch_bounds__(512, 4)
void gm_main(const float* __restrict__ x, const float* __restrict__ logits,
             const float* __restrict__ m2buf, const unsigned short* __restrict__ mf8,
             float* __restrict__ out)
{
    __shared__ __align__(16) unsigned char mldsT[Kc * 32]; // 16 KB fp8 means, kt-major
    __shared__ float wT[16 * 44];             // 2.75 KB fast-exp weight biases Wk
    __shared__ float x2p[ST];                 // 0.5 KB per-row sum(x^2)
    __shared__ float red[16];                 // [0..7] max, [8..15] expsum

    const int tid  = threadIdx.x;             // 0..511
    const int lane = tid & 63;
    const int wid  = tid >> 6;                // 0..7
    const int b    = blockIdx.x >> 3;
    const int s0   = (blockIdx.x & 7) * ST;
    const int q    = lane >> 4;               // k-octet of contraction dim
    const int ln   = lane & 15;
    const int rw   = wid * 16;                // this wave's 16-row subtile

    // stage means, kt-major: logical 8B entry (ch, kt) at physical byte
    // (ch<<8) + ((kt<<3) ^ (((ch>>2)&7)<<4)).  Swizzle bits (ch>>2)&7 = ln&7
    // are distinct within every 8-lane service group (R8: conflicts -18x).
    {
        const unsigned long long* src = (const unsigned long long*)mf8;
        #pragma unroll
        for (int j = 0; j < 4; ++j) {
            const int c   = tid + j * 512;           // 0..2047
            const int ktc = c >> 6;                  // component row >> 4
            const int ch  = ((c >> 2) & 15) * 4 + (c & 3);
            *(unsigned long long*)&mldsT[(ch << 8) + ((ktc << 3) ^ (((ch >> 2) & 7) << 4))]
                = src[c];
        }
    }

    // fast-exp weight bias Wk = (log2(w_k) + 127)*2^23 - c  (kt-major store)
    const float l = logits[b * Kc + tid];
    wT[(tid & 15) * 44 + (tid >> 4)] =
        fmaf((l - 0.5f * m2buf[tid]) * LOG2E, FE_SCALE, FE_BIAS);

    float mx = l;
    #pragma unroll
    for (int off = 32; off >= 1; off >>= 1) mx = fmaxf(mx, __shfl_xor(mx, off));
    if (lane == 0) red[wid] = mx;

    // x A-fragment direct from global (thread owns 8 of its row's 32 floats)
    const int row = rw + ln;
    long a;
    {
        const float4* xp = (const float4*)(x + ((size_t)b * Sc + s0 + row) * Dc) + q * 2;
        float4 v0 = xp[0], v1 = xp[1];
        int2 A;
        A.x = pkfp8<false>(v0.x * LOG2E, v0.y * LOG2E, 0);
        A.x = pkfp8<true >(v0.z * LOG2E, v0.w * LOG2E, A.x);
        A.y = pkfp8<false>(v1.x * LOG2E, v1.y * LOG2E, 0);
        A.y = pkfp8<true >(v1.z * LOG2E, v1.w * LOG2E, A.y);
        a = *(const long*)&A;
        float p = v0.x*v0.x + v0.y*v0.y + v0.z*v0.z + v0.w*v0.w
                + v1.x*v1.x + v1.y*v1.y + v1.z*v1.z + v1.w*v1.w;
        p += __shfl_xor(p, 16); p += __shfl_xor(p, 32);
        if (q == 0) x2p[row] = p;
    }
    __syncthreads();

    // finish lse start (max across the 8 waves parked in red[0..7]);
    // exact exp kept here (few per thread, enters every output directly)
    const float mxb = fmaxf(fmaxf(fmaxf(red[0], red[1]), fmaxf(red[2], red[3])),
                            fmaxf(fmaxf(red[4], red[5]), fmaxf(red[6], red[7])));
    float sm = EXP2F((l - mxb) * LOG2E);
    #pragma unroll
    for (int off = 32; off >= 1; off >>= 1) sm += __shfl_xor(sm, off);
    if (lane == 0) red[8 + wid] = sm;

    // hot loop: per 4-kt body = 2x ds_read_b128 (B) + 1x float4 (Wk) +
    // 4 MFMA + 16x {fma, cvt_i32, add}  (fast-exp2, weight pre-folded).
    // unroll 2 (of 8): bounds in-flight loads -> no spill (R8 lesson).
    const int ch   = ln * 4 + q;              // this thread's B-octet stream
    const int bbT  = ch << 8;
    const int swzv = (ln & 7) << 4;           // conflict-free spread bits
    const int ln44 = ln * 44;
    const f32x4 zero = {0.f, 0.f, 0.f, 0.f};
    float acc[4] = {0.f, 0.f, 0.f, 0.f};

    #pragma unroll 2
    for (int kt = 0; kt < 32; kt += 4) {
        const longx2 p01 = *(const longx2*)&mldsT[bbT + (((kt    ) << 3) ^ swzv)];
        const longx2 p23 = *(const longx2*)&mldsT[bbT + (((kt + 2) << 3) ^ swzv)];
        const float4 wv4 = *(const float4*)&wT[ln44 + kt];
        f32x4 d;
        d = __builtin_amdgcn_mfma_f32_16x16x32_fp8_fp8(a, p01.x, zero, 0, 0, 0);
        #pragma unroll
        for (int r = 0; r < 4; ++r)
            acc[r] += __int_as_float((int)fmaf(d[r], FE_SCALE, wv4.x));
        d = __builtin_amdgcn_mfma_f32_16x16x32_fp8_fp8(a, p01.y, zero, 0, 0, 0);
        #pragma unroll
        for (int r = 0; r < 4; ++r)
            acc[r] += __int_as_float((int)fmaf(d[r], FE_SCALE, wv4.y));
        d = __builtin_amdgcn_mfma_f32_16x16x32_fp8_fp8(a, p23.x, zero, 0, 0, 0);
        #pragma unroll
        for (int r = 0; r < 4; ++r)
            acc[r] += __int_as_float((int)fmaf(d[r], FE_SCALE, wv4.z));
        d = __builtin_amdgcn_mfma_f32_16x16x32_fp8_fp8(a, p23.y, zero, 0, 0, 0);
        #pragma unroll
        for (int r = 0; r < 4; ++r)
            acc[r] += __int_as_float((int)fmaf(d[r], FE_SCALE, wv4.w));
    }
    __syncthreads();                          // red[8..15] ready
    const float lse  = mxb + LN2 * LOG2F(((red[8]  + red[9])  + (red[10] + red[11]))
                                       + ((red[12] + red[13]) + (red[14] + red[15])));
    const float base = LOG_NORM + lse;

    // reduce over the 16 k-columns (low-4 lane bits), then write
    #pragma unroll
    for (int r = 0; r < 4; ++r) {
        float s = acc[r];
        s += __shfl_xor(s, 1); s += __shfl_xor(s, 2);
        s += __shfl_xor(s, 4); s += __shfl_xor(s, 8);
        if (ln == 0) {
            const int r0 = rw + q * 4 + r;       // C/D row = quad*4 + reg
            out[(size_t)b * Sc + s0 + r0] = 0.5f * x2p[r0] + base - LN2 * LOG2F(s);
        }
    }
}

extern "C" void kernel_launch(void* const* d_in, const int* in_sizes, int n_in,
                              void* d_out, int out_size, void* d_ws, size_t ws_size,
                              hipStream_t stream) {
    const float* x      = (const float*)d_in[0];
    const float* logits = (const float*)d_in[1];
    const float* means  = (const float*)d_in[2];
    float* out = (float*)d_out;
    (void)in_sizes; (void)n_in; (void)out_size; (void)ws_size;

    unsigned short* mf8   = (unsigned short*)d_ws;             // 16 KB (8192 u16)
    float*          m2buf = (float*)((char*)d_ws + 16384);     //  2 KB

    hipLaunchKernelGGL(gm_m2f8, dim3(32), dim3(256), 0, stream, means, mf8, m2buf);
    hipLaunchKernelGGL(gm_main, dim3(Bc * (Sc / ST)), dim3(512), 0, stream,
                       x, logits, m2buf, mf8, out);
}